// Round 15
// baseline (4345.472 us; speedup 1.0000x reference)
//
#include <hip/hip_runtime.h>
#include <hip/hip_bf16.h>

#define SS 128
#define TT 128
#define NBLK 256   // encoder grid
#define NBD  64    // decoder grid (8 hu/block, 2 MFMA tiles/wave)
#define FSTRIDE 16 // one flag per 64B cacheline

typedef __attribute__((ext_vector_type(8))) short bf16x8;
typedef __attribute__((ext_vector_type(4))) float f32x4;
typedef unsigned short ushort_t;

__device__ __forceinline__ float sigf(float x) { return 1.f / (1.f + __expf(-x)); }

__device__ __forceinline__ ushort_t f2bf(float f) {   // RNE f32 -> bf16
  unsigned b = __builtin_bit_cast(unsigned, f);
  return (ushort_t)((b + 0x7FFFu + ((b >> 16) & 1u)) >> 16);
}
__device__ __forceinline__ float bf2f(ushort_t u) {
  return __builtin_bit_cast(float, (unsigned)u << 16);
}

// Write-through coherent bf16 store (to MALL): cross-block producers.
__device__ __forceinline__ void cstoreh(ushort_t* p, ushort_t v) {
  __hip_atomic_store(p, v, __ATOMIC_RELAXED, __HIP_MEMORY_SCOPE_AGENT);
}

// Fragment-native ring index: element (k, b) of an x-slot lives at
//   ((k>>5)*256 + b*4 + ((k>>3)&3))*8 + (k&7)
// -> wave's MFMA B-frag load (lane=(l16,kg), iter ks) is a CONTIGUOUS 1KB.
__device__ __forceinline__ int xidx(int k, int b) {
  return (((k >> 5) * 256 + b * 4 + ((k >> 3) & 3)) << 3) + (k & 7);
}

// ---------------------------------------------------------------------------
// R8 master-relay barrier (best measured), templated on block count.
template<int NB>
__device__ __forceinline__ void gbar(unsigned* flags, unsigned gen) {
  __syncthreads();
  int tid = threadIdx.x;
  unsigned* arr = flags;
  unsigned* go  = flags + NB * FSTRIDE;
  if (blockIdx.x == 0) {
    if (tid > 0 && tid < NB) {
      int guard = 0;
      while (__hip_atomic_load(&arr[tid * FSTRIDE], __ATOMIC_RELAXED,
                               __HIP_MEMORY_SCOPE_AGENT) < gen &&
             ++guard < (1 << 20))
        __builtin_amdgcn_s_sleep(1);
    }
    __syncthreads();
    if (tid < NB)
      __hip_atomic_store(&go[tid * FSTRIDE], gen, __ATOMIC_RELAXED,
                         __HIP_MEMORY_SCOPE_AGENT);
  } else {
    if (tid == 0) {
      asm volatile("s_waitcnt vmcnt(0)" ::: "memory");
      __hip_atomic_store(&arr[blockIdx.x * FSTRIDE], gen, __ATOMIC_RELAXED,
                         __HIP_MEMORY_SCOPE_AGENT);
      int guard = 0;
      while (__hip_atomic_load(&go[blockIdx.x * FSTRIDE], __ATOMIC_RELAXED,
                               __HIP_MEMORY_SCOPE_AGENT) < gen &&
             ++guard < (1 << 20))
        __builtin_amdgcn_s_sleep(1);
    }
    __syncthreads();
  }
  asm volatile("" ::: "memory");
}

// ---------------------------------------------------------------------------
// Embedding gather -> bf16 [seq*64][512]
__global__ void k_embed_bf(const float* __restrict__ emb, const int* __restrict__ toks,
                           ushort_t* __restrict__ out, int seqlen) {
  int s = blockIdx.x >> 6, b = blockIdx.x & 63;
  int tok = toks[b * seqlen + s];
  float4 v = ((const float4*)(emb + (size_t)tok * 512))[threadIdx.x];
  unsigned lo = (unsigned)f2bf(v.x) | ((unsigned)f2bf(v.y) << 16);
  unsigned hi = (unsigned)f2bf(v.z) | ((unsigned)f2bf(v.w) << 16);
  uint2 pk = {lo, hi};
  *(uint2*)&out[(size_t)blockIdx.x * 512 + threadIdx.x * 4] = pk;
}

// Cast weights to bf16. wBF (aliases r2; all reads BEFORE dec_persist):
// slot0=enc_w_ih0[2048][512], slot1=enc_w_ih1, slot2=dec_w_ih0[:, 0:512].
// predBF (separate, NON-aliased: read AFTER dec_persist) = pred_w[512][512].
__global__ void k_castw(const float* __restrict__ s0, const float* __restrict__ s1,
                        const float* __restrict__ s2, const float* __restrict__ s3,
                        ushort_t* __restrict__ wBF, ushort_t* __restrict__ predBF) {
  int row = blockIdx.x, which = blockIdx.y;
  if (which == 3 && row >= 512) return;
  const float* src = (which == 0) ? s0 + (size_t)row * 512
                   : (which == 1) ? s1 + (size_t)row * 512
                   : (which == 2) ? s2 + (size_t)row * 1024
                                  : s3 + (size_t)row * 512;
  float4 v = ((const float4*)src)[threadIdx.x];
  unsigned lo = (unsigned)f2bf(v.x) | ((unsigned)f2bf(v.y) << 16);
  unsigned hi = (unsigned)f2bf(v.z) | ((unsigned)f2bf(v.w) << 16);
  uint2 pk = {lo, hi};
  if (which == 3)
    *(uint2*)&predBF[(size_t)row * 512 + threadIdx.x * 4] = pk;
  else
    *(uint2*)&wBF[((size_t)which * 2048 + row) * 512 + threadIdx.x * 4] = pk;
}

// ---------------------------------------------------------------------------
// bf16 MFMA GEMM, K=512. MODE 1: gate precompute, N=2048,
//   GT[((m>>6)*2048 + n)*64 + (m&63)] = X·W + b1 + b2
// MODE 2: final projection, N=512, out[((m&63)*512+n)*128+(m>>6)] = X·W + b1
__global__ __launch_bounds__(256) void gemm_bf(
    const ushort_t* __restrict__ X, const ushort_t* __restrict__ W,
    const float* __restrict__ b1, const float* __restrict__ b2,
    float* __restrict__ C, int MODE) {
  __shared__ ushort_t Xs[128 * 72];
  __shared__ ushort_t Ws[128 * 72];
  __shared__ float sbias[128];
  int n0 = blockIdx.x * 128, m0 = blockIdx.y * 128;
  int tid = threadIdx.x;
  int lane = tid & 63;
  int wv = __builtin_amdgcn_readfirstlane(tid >> 6);
  int h_m = (wv >> 1) * 64, h_n = (wv & 1) * 64;
  int l16 = lane & 15, l4 = (lane >> 4) * 4, k8 = (lane >> 4) * 8;
  if (tid < 128) sbias[tid] = b1[n0 + tid] + (b2 ? b2[n0 + tid] : 0.f);
  f32x4 acc[4][4] = {};
  int lrow = tid >> 1, lhf = (tid & 1) * 32;
  for (int k0 = 0; k0 < 512; k0 += 64) {
    __syncthreads();
    const ushort_t* xs = X + (size_t)(m0 + lrow) * 512 + k0 + lhf;
    const ushort_t* wsrc = W + (size_t)(n0 + lrow) * 512 + k0 + lhf;
#pragma unroll
    for (int q = 0; q < 4; ++q) {
      *(bf16x8*)&Xs[lrow * 72 + lhf + q * 8] = *(const bf16x8*)(xs + q * 8);
      *(bf16x8*)&Ws[lrow * 72 + lhf + q * 8] = *(const bf16x8*)(wsrc + q * 8);
    }
    __syncthreads();
#pragma unroll
    for (int kk = 0; kk < 2; ++kk) {
#pragma unroll
      for (int mt = 0; mt < 4; ++mt) {
        bf16x8 af = *(const bf16x8*)&Xs[(h_m + mt * 16 + l16) * 72 + kk * 32 + k8];
#pragma unroll
        for (int nt = 0; nt < 4; ++nt) {
          bf16x8 bf = *(const bf16x8*)&Ws[(h_n + nt * 16 + l16) * 72 + kk * 32 + k8];
          acc[mt][nt] = __builtin_amdgcn_mfma_f32_16x16x32_bf16(af, bf, acc[mt][nt], 0, 0, 0);
        }
      }
    }
  }
  if (MODE == 1) {
    int s = (m0 + h_m) >> 6;
#pragma unroll
    for (int nt = 0; nt < 4; ++nt) {
      int n = n0 + h_n + nt * 16 + l16;
      float bias = sbias[h_n + nt * 16 + l16];
#pragma unroll
      for (int mt = 0; mt < 4; ++mt) {
        f32x4 v = acc[mt][nt];
        v[0] += bias; v[1] += bias; v[2] += bias; v[3] += bias;
        *(f32x4*)&C[((size_t)s * 2048 + n) * 64 + mt * 16 + l4] = v;
      }
    }
  } else {
#pragma unroll
    for (int nt = 0; nt < 4; ++nt) {
      int n = n0 + h_n + nt * 16 + l16;
      float bias = sbias[h_n + nt * 16 + l16];
#pragma unroll
      for (int mt = 0; mt < 4; ++mt) {
#pragma unroll
        for (int r = 0; r < 4; ++r) {
          int m = m0 + h_m + mt * 16 + l4 + r;
          C[((size_t)(m & 63) * 512 + n) * 128 + (m >> 6)] = acc[mt][nt][r] + bias;
        }
      }
    }
  }
}

// ---------------------------------------------------------------------------
// Persistent encoder layer: K=256, ring ringE[129][2][frag-native 64x256].
// LOUT=0: lout bf16 [8192][512] (feeds layer-1 GEMM). LOUT=1: bf16 [64][128][512].
template<int LOUT>
__global__ __launch_bounds__(256, 1) void enc_persist(
    const float* __restrict__ GT,     // [128][2048][64] input gates fp32
    const float* __restrict__ whh,    // [2][1024][256] this layer fp32
    ushort_t* __restrict__ ringE,     // [129][2][16384] bf16 frag-native
    ushort_t* __restrict__ lout,
    ushort_t* __restrict__ hFin,      // dec ring slot0 (frag-native [64][1024])
    float* __restrict__ cFin,         // [512][64] fp32
    unsigned* bar) {
  int nb = blockIdx.x;
  int d = nb >> 7, nbL = nb & 127;
  int tid = threadIdx.x;
  int lane = tid & 63;
  int wv = __builtin_amdgcn_readfirstlane(tid >> 6);
  int l16 = lane & 15, kg = lane >> 4;
  __shared__ ushort_t wE[16 * 264];

  for (int idx = tid; idx < 16 * 256; idx += 256) {
    int m = idx >> 8, k = idx & 255;
    float v = 0.f;
    if (m < 8)
      v = whh[(size_t)d * 262144 +
              (size_t)((m & 3) * 256 + nbL + 128 * (m >> 2)) * 256 + k];
    wE[m * 264 + k] = f2bf(v);
  }
  __syncthreads();

  int b = wv * 16 + l16;
  int hu = nbL + 128 * kg;            // epilogue lanes (<32)
  float creg = 0.f;
  const ushort_t* wp = wE + l16 * 264 + kg * 8;

  for (int t = 0; t < SS; ++t) {
    int s = d ? (SS - 1 - t) : t;
    const ushort_t* xb = ringE + (size_t)(t * 2 + d) * 16384 +
                         wv * 512 + l16 * 32 + kg * 8;
    bf16x8 bfr[8];
#pragma unroll
    for (int ks = 0; ks < 8; ++ks) bfr[ks] = *(const bf16x8*)(xb + ks * 2048);
    float gi[4];
    if (lane < 32) {
#pragma unroll
      for (int r = 0; r < 4; ++r)
        gi[r] = GT[((size_t)s * 2048 + d * 1024 + r * 256 + hu) * 64 + b];
    }
    f32x4 acc = {0.f, 0.f, 0.f, 0.f};
#pragma unroll
    for (int ks = 0; ks < 8; ++ks) {
      bf16x8 af = *(const bf16x8*)(wp + ks * 32);
      acc = __builtin_amdgcn_mfma_f32_16x16x32_bf16(af, bfr[ks], acc, 0, 0, 0);
    }
    if (lane < 32) {
      float g4[4];
#pragma unroll
      for (int r = 0; r < 4; ++r) g4[r] = acc[r] + gi[r];
      float ig = sigf(g4[0]), fg = sigf(g4[1]), gg = tanhf(g4[2]), og = sigf(g4[3]);
      creg = fg * creg + ig * gg;
      float hn = og * tanhf(creg);
      cstoreh(&ringE[(size_t)((t + 1) * 2 + d) * 16384 + xidx(hu, b)], f2bf(hn));
      if (LOUT == 0)
        lout[((size_t)s * 64 + b) * 512 + d * 256 + hu] = f2bf(hn);
      else
        lout[(size_t)b * 65536 + (size_t)s * 512 + d * 256 + hu] = f2bf(hn);
      if (t == SS - 1) {
        hFin[xidx(512 + d * 256 + hu, b)] = f2bf(hn);
        cFin[(d * 256 + hu) * 64 + b] = creg;
      }
    }
    if (t < SS - 1) gbar<NBLK>(bar, (unsigned)(t + 1));
  }
}

// ---------------------------------------------------------------------------
// Persistent decoder, NBD=64 blocks: block owns 8 hu = {nb + 64*j}, j=0..7.
// Two 16-row MFMA tiles per wave: tile T rows mm = jl*4+g -> j = T*4+jl.
// Lane (kg,l16) tile T holds gates g=0..3 (regs) of hu = nb + 64*(kg+4T),
// batch b = wv*16+l16. All 64 lanes produce 2 h each. Halves cross-block
// x-read duplication vs NBD=128 (8MB/phase) at 64 MFMA/wave/phase.
// Rings (frag-native [64][1024]): r0=[feed|h0], r1=[-|h1], r2=[ctx|-].
__global__ __launch_bounds__(256, 1) void dec_persist(
    const float* __restrict__ GdT,    // [128][2048][64] emb gates fp32
    const float* __restrict__ w_ih0, const float* __restrict__ w_hh0,
    const float* __restrict__ w_ih1, const float* __restrict__ w_hh1,
    const float* __restrict__ b_ih1, const float* __restrict__ b_hh1,
    const float* __restrict__ attn_w,
    const ushort_t* __restrict__ enc_out,   // [64][128][512] bf16
    const int* __restrict__ src_tokens,
    const float* __restrict__ c0T, const float* __restrict__ c1T,  // [512][64]
    ushort_t* __restrict__ r0, ushort_t* __restrict__ r1,
    ushort_t* __restrict__ r2,
    ushort_t* __restrict__ houtsB,    // [8192][512] bf16
    unsigned* bar) {
  int nb = blockIdx.x;                // 0..63
  int tid = threadIdx.x;
  int lane = tid & 63;
  int wv = __builtin_amdgcn_readfirstlane(tid >> 6);
  int l16 = lane & 15, kg = lane >> 4;
  __shared__ ushort_t wAl[32 * 1032];   // 66KB: rows m=T*16+jl*4+g -> W row g*512+nb+64*(T*4+jl)
  __shared__ ushort_t wBl[32 * 1032];   // 66KB
  __shared__ ushort_t wDl[8 * 1032];    // 16.5KB: row m -> attn_w row nb*8+m
  __shared__ float h1s[512];
  __shared__ float sc[128];

  // ---- stage bf16 weights (once) ----
  for (int idx = tid; idx < 32768; idx += 256) {
    int m = idx >> 10, k = idx & 1023;
    int j = m >> 2, g = m & 3;        // j = T*4+jl in [0,8)
    int row = g * 512 + nb + 64 * j;
    float va = (k < 512) ? w_ih0[(size_t)row * 1024 + 512 + k]
                         : w_hh0[(size_t)row * 512 + (k - 512)];
    float vb = (k < 512) ? w_ih1[(size_t)row * 512 + k]
                         : w_hh1[(size_t)row * 512 + (k - 512)];
    wAl[m * 1032 + k] = f2bf(va);
    wBl[m * 1032 + k] = f2bf(vb);
  }
  for (int idx = tid; idx < 8192; idx += 256) {
    int m = idx >> 10, k = idx & 1023;
    wDl[m * 1032 + k] = f2bf(attn_w[(size_t)(nb * 8 + m) * 1024 + k]);
  }
  __syncthreads();

  int b = wv * 16 + l16;
  int hu0 = nb + 64 * kg;             // tile 0
  int hu1 = nb + 64 * (kg + 4);       // tile 1
  float c0r[2], c1r[2], bias1[2][4];
  c0r[0] = c0T[hu0 * 64 + b]; c0r[1] = c0T[hu1 * 64 + b];
  c1r[0] = c1T[hu0 * 64 + b]; c1r[1] = c1T[hu1 * 64 + b];
#pragma unroll
  for (int r = 0; r < 4; ++r) {
    bias1[0][r] = b_ih1[r * 512 + hu0] + b_hh1[r * 512 + hu0];
    bias1[1][r] = b_ih1[r * 512 + hu1] + b_hh1[r * 512 + hu1];
  }
  const ushort_t* wpA0 = wAl + l16 * 1032 + kg * 8;
  const ushort_t* wpA1 = wAl + (16 + l16) * 1032 + kg * 8;
  const ushort_t* wpB0 = wBl + l16 * 1032 + kg * 8;
  const ushort_t* wpB1 = wBl + (16 + l16) * 1032 + kg * 8;
  const ushort_t* wpD  = wDl + l16 * 1032 + kg * 8;   // valid only l16<8
  int fragoff = wv * 512 + l16 * 32 + kg * 8;         // frag-native wave base

  for (int t = 0; t < TT; ++t) {
    unsigned gb = (unsigned)(t * 4);
    size_t sC = (size_t)t * 65536, sN = (size_t)(t + 1) * 65536;
    // ---- A: cell0, x = [feed(t) | h0(t)] = r0 slot t ----
    {
      const ushort_t* xb = r0 + sC + fragoff;
      bf16x8 bfr[32];
#pragma unroll
      for (int ks = 0; ks < 32; ++ks) bfr[ks] = *(const bf16x8*)(xb + ks * 2048);
      float giA[2][4];
#pragma unroll
      for (int r = 0; r < 4; ++r) {
        giA[0][r] = GdT[((size_t)t * 2048 + r * 512 + hu0) * 64 + b];
        giA[1][r] = GdT[((size_t)t * 2048 + r * 512 + hu1) * 64 + b];
      }
      f32x4 a0 = {0.f, 0.f, 0.f, 0.f}, a1 = {0.f, 0.f, 0.f, 0.f};
#pragma unroll
      for (int ks = 0; ks < 32; ++ks) {
        a0 = __builtin_amdgcn_mfma_f32_16x16x32_bf16(
            *(const bf16x8*)(wpA0 + ks * 32), bfr[ks], a0, 0, 0, 0);
        a1 = __builtin_amdgcn_mfma_f32_16x16x32_bf16(
            *(const bf16x8*)(wpA1 + ks * 32), bfr[ks], a1, 0, 0, 0);
      }
#pragma unroll
      for (int T = 0; T < 2; ++T) {
        f32x4 acc = T ? a1 : a0;
        int hu = T ? hu1 : hu0;
        float ig = sigf(acc[0] + giA[T][0]), fg = sigf(acc[1] + giA[T][1]);
        float gg = tanhf(acc[2] + giA[T][2]), og = sigf(acc[3] + giA[T][3]);
        c0r[T] = fg * c0r[T] + ig * gg;
        float hn = og * tanhf(c0r[T]);
        cstoreh(&r0[sN + xidx(512 + hu, b)], f2bf(hn));   // h0(t+1-slot)
      }
    }
    gbar<NBD>(bar, gb + 1);
    // ---- B: cell1, x = [h0(t) from r0 nxt | h1(t-1) from r1 cur] ----
    {
      bf16x8 bfr[32];
      const ushort_t* xh0 = r0 + sN + fragoff;
      const ushort_t* xh1 = r1 + sC + fragoff;
#pragma unroll
      for (int ks = 0; ks < 16; ++ks) bfr[ks] = *(const bf16x8*)(xh0 + (16 + ks) * 2048);
#pragma unroll
      for (int ks = 16; ks < 32; ++ks) bfr[ks] = *(const bf16x8*)(xh1 + ks * 2048);
      f32x4 a0 = {0.f, 0.f, 0.f, 0.f}, a1 = {0.f, 0.f, 0.f, 0.f};
#pragma unroll
      for (int ks = 0; ks < 32; ++ks) {
        a0 = __builtin_amdgcn_mfma_f32_16x16x32_bf16(
            *(const bf16x8*)(wpB0 + ks * 32), bfr[ks], a0, 0, 0, 0);
        a1 = __builtin_amdgcn_mfma_f32_16x16x32_bf16(
            *(const bf16x8*)(wpB1 + ks * 32), bfr[ks], a1, 0, 0, 0);
      }
#pragma unroll
      for (int T = 0; T < 2; ++T) {
        f32x4 acc = T ? a1 : a0;
        int hu = T ? hu1 : hu0;
        float ig = sigf(acc[0] + bias1[T][0]), fg = sigf(acc[1] + bias1[T][1]);
        float gg = tanhf(acc[2] + bias1[T][2]), og = sigf(acc[3] + bias1[T][3]);
        c1r[T] = fg * c1r[T] + ig * gg;
        float hn = og * tanhf(c1r[T]);
        cstoreh(&r1[sN + xidx(512 + hu, b)], f2bf(hn));   // h1(t)
      }
    }
    gbar<NBD>(bar, gb + 2);
    // ---- C: attention (all 64 blocks; block nb = batch nb; bf16 enc_out) ----
    {
      const ushort_t* eb = enc_out + (size_t)nb * 65536;
      for (int i = tid; i < 512; i += 256)
        h1s[i] = bf2f(r1[sN + xidx(512 + i, nb)]);
      __syncthreads();
      {
        int s2 = tid >> 1, half = tid & 1;
        const ushort_t* er = eb + (size_t)s2 * 512 + half * 256;
        const float* hh = h1s + half * 256;
        float a = 0.f;
#pragma unroll 4
        for (int k = 0; k < 256; k += 8) {
          bf16x8 ev = *(const bf16x8*)(er + k);
#pragma unroll
          for (int i = 0; i < 8; ++i)
            a += bf2f((ushort_t)ev[i]) * hh[k + i];
        }
        a += __shfl_xor(a, 1);
        if (!half) sc[s2] = (src_tokens[nb * SS + s2] == 0) ? -1e30f : a;
      }
      __syncthreads();
      if (tid < 64) {
        float m = fmaxf(sc[tid], sc[tid + 64]);
        for (int off = 32; off; off >>= 1) m = fmaxf(m, __shfl_xor(m, off));
        float e0 = __expf(sc[tid] - m), e1 = __expf(sc[tid + 64] - m);
        float ssum = e0 + e1;
        for (int off = 32; off; off >>= 1) ssum += __shfl_xor(ssum, off);
        float inv = 1.f / ssum;
        sc[tid] = e0 * inv; sc[tid + 64] = e1 * inv;
      }
      __syncthreads();
      float a0 = 0.f, a1 = 0.f;
      for (int s2 = 0; s2 < 128; ++s2) {
        float p_ = sc[s2];
        const ushort_t* er = eb + (size_t)s2 * 512;
        a0 += p_ * bf2f(er[tid]);
        a1 += p_ * bf2f(er[tid + 256]);
      }
      cstoreh(&r2[sC + xidx(tid, nb)], f2bf(a0));
      cstoreh(&r2[sC + xidx(tid + 256, nb)], f2bf(a1));
    }
    gbar<NBD>(bar, gb + 3);
    // ---- D: outproj tanh([ctx r2 cur | h1 r1 nxt] @ wD^T), o = nb*8+m ----
    {
      bf16x8 bfr[32];
      const ushort_t* xc = r2 + sC + fragoff;
      const ushort_t* xh1 = r1 + sN + fragoff;
#pragma unroll
      for (int ks = 0; ks < 16; ++ks) bfr[ks] = *(const bf16x8*)(xc + ks * 2048);
#pragma unroll
      for (int ks = 16; ks < 32; ++ks) bfr[ks] = *(const bf16x8*)(xh1 + ks * 2048);
      f32x4 acc = {0.f, 0.f, 0.f, 0.f};
      bf16x8 zf = {};
#pragma unroll
      for (int ks = 0; ks < 32; ++ks) {
        bf16x8 af = (l16 < 8) ? *(const bf16x8*)(wpD + ks * 32) : zf;
        acc = __builtin_amdgcn_mfma_f32_16x16x32_bf16(af, bfr[ks], acc, 0, 0, 0);
      }
      if (kg < 2) {   // rows kg*4+r < 8 hold the real outputs
#pragma unroll
        for (int r = 0; r < 4; ++r) {
          int o = nb * 8 + kg * 4 + r;
          float v = tanhf(acc[r]);
          ushort_t vb = f2bf(v);
          cstoreh(&r0[sN + xidx(o, b)], vb);            // feed(t+1-slot)
          houtsB[((size_t)t * 64 + b) * 512 + o] = vb;
        }
      }
    }
    if (t < TT - 1) gbar<NBD>(bar, gb + 4);
  }
}

// ---------------------------------------------------------------------------
extern "C" void kernel_launch(void* const* d_in, const int* in_sizes, int n_in,
                              void* d_out, int out_size, void* d_ws, size_t ws_size,
                              hipStream_t stream) {
  const int*   src_tokens = (const int*)d_in[0];
  const int*   dst        = (const int*)d_in[2];
  const float* emb_in     = (const float*)d_in[3];
  const float* emb_out    = (const float*)d_in[4];
  const float* enc_w_ih0  = (const float*)d_in[5];
  const float* enc_w_ih1  = (const float*)d_in[6];
  const float* enc_w_hh   = (const float*)d_in[7];
  const float* enc_b_ih   = (const float*)d_in[8];
  const float* enc_b_hh   = (const float*)d_in[9];
  const float* dec_w_ih0  = (const float*)d_in[10];
  const float* dec_w_hh0  = (const float*)d_in[11];
  const float* dec_b_ih0  = (const float*)d_in[12];
  const float* dec_b_hh0  = (const float*)d_in[13];
  const float* dec_w_ih1  = (const float*)d_in[14];
  const float* dec_w_hh1  = (const float*)d_in[15];
  const float* dec_b_ih1  = (const float*)d_in[16];
  const float* dec_b_hh1  = (const float*)d_in[17];
  const float* attn_w     = (const float*)d_in[18];
  const float* pred_w     = (const float*)d_in[19];
  const float* pred_b     = (const float*)d_in[20];
  float* out = (float*)d_out;

  float* ws       = (float*)d_ws;
  ushort_t* houtsB = (ushort_t*)ws;                 // [8192][512] bf16
  float* GT       = ws + 4194304;                   // 16,777,216 f
  ushort_t* encOutB = (ushort_t*)(ws + 20971520);   // [64][128][512] bf16 (2,097,152 f)
  ushort_t* predBF  = (ushort_t*)(ws + 23068672);   // [512][512] bf16 -- NOT aliased
  ushort_t* r0    = (ushort_t*)(ws + 25165824);     // 129*65536 bf16 frag-native
  ushort_t* r1    = (ushort_t*)(ws + 29392896);
  ushort_t* r2    = (ushort_t*)(ws + 33619968);     // 128 slots; wBF alias pre-dec
  ushort_t* wBF   = r2;                             // [3][2048][512] bf16 (reads all pre-dec)
  ushort_t* ringE = (ushort_t*)(ws + 37814272);     // 129*2*16384 bf16
  float* c0T      = ws + 39927808;                  // 32,768
  float* c1T      = ws + 39960576;                  // 32,768
  unsigned* barA  = (unsigned*)(ws + 39993344);     // 3 x 8192 uints
  unsigned* barB  = barA + 8192;
  unsigned* barC  = barB + 8192;                    // dec uses 2*64*16 = 2048
  ushort_t* U     = (ushort_t*)(ws + 40017920);     // [8192][512] bf16 staging

  hipMemsetAsync(barA, 0, 3 * 8192 * sizeof(unsigned), stream);
  hipMemsetAsync(r0, 0, 65536 * sizeof(ushort_t), stream);     // slot 0
  hipMemsetAsync(r1, 0, 65536 * sizeof(ushort_t), stream);     // slot 0
  hipMemsetAsync(ringE, 0, 32768 * sizeof(ushort_t), stream);  // slot 0

  // ---- One-time weight cast (wBF aliases r2 -- consumed before dec;
  //      pred_w goes to predBF which nothing else touches)
  k_castw<<<dim3(2048, 4), 128, 0, stream>>>(enc_w_ih0, enc_w_ih1, dec_w_ih0,
                                             pred_w, wBF, predBF);

  // ---- Encoder ----
  k_embed_bf<<<dim3(8192), 128, 0, stream>>>(emb_in, src_tokens, U, SS);
  gemm_bf<<<dim3(16, 64), 256, 0, stream>>>(U, wBF, enc_b_ih, enc_b_hh, GT, 1);
  enc_persist<0><<<dim3(NBLK), 256, 0, stream>>>(GT, enc_w_hh, ringE, U,
                                                 r0, c0T, barA);
  gemm_bf<<<dim3(16, 64), 256, 0, stream>>>(U, wBF + 1048576,
                                            enc_b_ih + 2048, enc_b_hh + 2048, GT, 1);
  enc_persist<1><<<dim3(NBLK), 256, 0, stream>>>(GT, enc_w_hh + 524288, ringE,
                                                 encOutB, r1, c1T, barB);

  // ---- Decoder precompute (emb part of cell0 gates) ----
  k_embed_bf<<<dim3(8192), 128, 0, stream>>>(emb_out, dst, U, TT);
  gemm_bf<<<dim3(16, 64), 256, 0, stream>>>(U, wBF + 2097152,
                                            dec_b_ih0, dec_b_hh0, GT, 1);

  // ---- Decoder (persistent, 64 blocks, 2 tiles/wave) ----
  dec_persist<<<dim3(NBD), 256, 0, stream>>>(
      GT, dec_w_ih0, dec_w_hh0, dec_w_ih1, dec_w_hh1, dec_b_ih1, dec_b_hh1,
      attn_w, encOutB, src_tokens, c0T, c1T, r0, r1, r2, houtsB, barC);

  // ---- Final projection (bf16 MFMA) straight to [B][OUT][T] ----
  gemm_bf<<<dim3(4, 64), 256, 0, stream>>>(houtsB, predBF,
                                           pred_b, nullptr, out, 2);
}

// Round 16
// 4338.581 us; speedup vs baseline: 1.0016x; 1.0016x over previous
//
#include <hip/hip_runtime.h>
#include <hip/hip_bf16.h>

#define SS 128
#define TT 128
#define NBLK 256   // encoder grid
#define NBD  128   // decoder grid (R14 best: full 16-row MFMA tiles)
#define FSTRIDE 16 // one flag per 64B cacheline

typedef __attribute__((ext_vector_type(8))) short bf16x8;
typedef __attribute__((ext_vector_type(4))) float f32x4;
typedef unsigned short ushort_t;

__device__ __forceinline__ float sigf(float x) { return 1.f / (1.f + __expf(-x)); }

__device__ __forceinline__ ushort_t f2bf(float f) {   // RNE f32 -> bf16
  unsigned b = __builtin_bit_cast(unsigned, f);
  return (ushort_t)((b + 0x7FFFu + ((b >> 16) & 1u)) >> 16);
}
__device__ __forceinline__ float bf2f(ushort_t u) {
  return __builtin_bit_cast(float, (unsigned)u << 16);
}

// Write-through coherent bf16 store (to MALL): cross-block producers.
__device__ __forceinline__ void cstoreh(ushort_t* p, ushort_t v) {
  __hip_atomic_store(p, v, __ATOMIC_RELAXED, __HIP_MEMORY_SCOPE_AGENT);
}

// Fragment-native ring index: element (k, b) of an x-slot lives at
//   ((k>>5)*256 + b*4 + ((k>>3)&3))*8 + (k&7)
// -> wave's MFMA B-frag load (lane=(l16,kg), iter ks) is a CONTIGUOUS 1KB.
__device__ __forceinline__ int xidx(int k, int b) {
  return (((k >> 5) * 256 + b * 4 + ((k >> 3) & 3)) << 3) + (k & 7);
}

// ---------------------------------------------------------------------------
// Single-hop peer-poll barrier: thread0 drains stores + posts arrival flag;
// EVERY thread polls one peer's flag (tid & (NB-1)) until >= gen. Latency from
// last arrival = store visibility + one poll iteration (1 fabric RT), vs the
// R8 master-relay's two serialized RTs (master-detect -> go-store -> re-poll).
template<int NB>
__device__ __forceinline__ void gbar(unsigned* flags, unsigned gen) {
  __syncthreads();
  int tid = threadIdx.x;
  if (tid == 0) {
    asm volatile("s_waitcnt vmcnt(0)" ::: "memory");
    __hip_atomic_store(&flags[blockIdx.x * FSTRIDE], gen, __ATOMIC_RELAXED,
                       __HIP_MEMORY_SCOPE_AGENT);
  }
  {
    int who = tid & (NB - 1);
    int guard = 0;
    while (__hip_atomic_load(&flags[who * FSTRIDE], __ATOMIC_RELAXED,
                             __HIP_MEMORY_SCOPE_AGENT) < gen &&
           ++guard < (1 << 20))
      __builtin_amdgcn_s_sleep(1);
  }
  __syncthreads();
  asm volatile("" ::: "memory");
}

// ---------------------------------------------------------------------------
// Embedding gather -> bf16 [seq*64][512]
__global__ void k_embed_bf(const float* __restrict__ emb, const int* __restrict__ toks,
                           ushort_t* __restrict__ out, int seqlen) {
  int s = blockIdx.x >> 6, b = blockIdx.x & 63;
  int tok = toks[b * seqlen + s];
  float4 v = ((const float4*)(emb + (size_t)tok * 512))[threadIdx.x];
  unsigned lo = (unsigned)f2bf(v.x) | ((unsigned)f2bf(v.y) << 16);
  unsigned hi = (unsigned)f2bf(v.z) | ((unsigned)f2bf(v.w) << 16);
  uint2 pk = {lo, hi};
  *(uint2*)&out[(size_t)blockIdx.x * 512 + threadIdx.x * 4] = pk;
}

// Cast weights to bf16. wBF (aliases r2; all reads BEFORE dec_persist):
// slot0=enc_w_ih0[2048][512], slot1=enc_w_ih1, slot2=dec_w_ih0[:, 0:512].
// predBF (separate, NON-aliased: read AFTER dec_persist) = pred_w[512][512].
__global__ void k_castw(const float* __restrict__ s0, const float* __restrict__ s1,
                        const float* __restrict__ s2, const float* __restrict__ s3,
                        ushort_t* __restrict__ wBF, ushort_t* __restrict__ predBF) {
  int row = blockIdx.x, which = blockIdx.y;
  if (which == 3 && row >= 512) return;
  const float* src = (which == 0) ? s0 + (size_t)row * 512
                   : (which == 1) ? s1 + (size_t)row * 512
                   : (which == 2) ? s2 + (size_t)row * 1024
                                  : s3 + (size_t)row * 512;
  float4 v = ((const float4*)src)[threadIdx.x];
  unsigned lo = (unsigned)f2bf(v.x) | ((unsigned)f2bf(v.y) << 16);
  unsigned hi = (unsigned)f2bf(v.z) | ((unsigned)f2bf(v.w) << 16);
  uint2 pk = {lo, hi};
  if (which == 3)
    *(uint2*)&predBF[(size_t)row * 512 + threadIdx.x * 4] = pk;
  else
    *(uint2*)&wBF[((size_t)which * 2048 + row) * 512 + threadIdx.x * 4] = pk;
}

// ---------------------------------------------------------------------------
// bf16 MFMA GEMM, K=512. MODE 1: gate precompute, N=2048,
//   GT[((m>>6)*2048 + n)*64 + (m&63)] = X·W + b1 + b2
// MODE 2: final projection, N=512, out[((m&63)*512+n)*128+(m>>6)] = X·W + b1
__global__ __launch_bounds__(256) void gemm_bf(
    const ushort_t* __restrict__ X, const ushort_t* __restrict__ W,
    const float* __restrict__ b1, const float* __restrict__ b2,
    float* __restrict__ C, int MODE) {
  __shared__ ushort_t Xs[128 * 72];
  __shared__ ushort_t Ws[128 * 72];
  __shared__ float sbias[128];
  int n0 = blockIdx.x * 128, m0 = blockIdx.y * 128;
  int tid = threadIdx.x;
  int lane = tid & 63;
  int wv = __builtin_amdgcn_readfirstlane(tid >> 6);
  int h_m = (wv >> 1) * 64, h_n = (wv & 1) * 64;
  int l16 = lane & 15, l4 = (lane >> 4) * 4, k8 = (lane >> 4) * 8;
  if (tid < 128) sbias[tid] = b1[n0 + tid] + (b2 ? b2[n0 + tid] : 0.f);
  f32x4 acc[4][4] = {};
  int lrow = tid >> 1, lhf = (tid & 1) * 32;
  for (int k0 = 0; k0 < 512; k0 += 64) {
    __syncthreads();
    const ushort_t* xs = X + (size_t)(m0 + lrow) * 512 + k0 + lhf;
    const ushort_t* wsrc = W + (size_t)(n0 + lrow) * 512 + k0 + lhf;
#pragma unroll
    for (int q = 0; q < 4; ++q) {
      *(bf16x8*)&Xs[lrow * 72 + lhf + q * 8] = *(const bf16x8*)(xs + q * 8);
      *(bf16x8*)&Ws[lrow * 72 + lhf + q * 8] = *(const bf16x8*)(wsrc + q * 8);
    }
    __syncthreads();
#pragma unroll
    for (int kk = 0; kk < 2; ++kk) {
#pragma unroll
      for (int mt = 0; mt < 4; ++mt) {
        bf16x8 af = *(const bf16x8*)&Xs[(h_m + mt * 16 + l16) * 72 + kk * 32 + k8];
#pragma unroll
        for (int nt = 0; nt < 4; ++nt) {
          bf16x8 bf = *(const bf16x8*)&Ws[(h_n + nt * 16 + l16) * 72 + kk * 32 + k8];
          acc[mt][nt] = __builtin_amdgcn_mfma_f32_16x16x32_bf16(af, bf, acc[mt][nt], 0, 0, 0);
        }
      }
    }
  }
  if (MODE == 1) {
    int s = (m0 + h_m) >> 6;
#pragma unroll
    for (int nt = 0; nt < 4; ++nt) {
      int n = n0 + h_n + nt * 16 + l16;
      float bias = sbias[h_n + nt * 16 + l16];
#pragma unroll
      for (int mt = 0; mt < 4; ++mt) {
        f32x4 v = acc[mt][nt];
        v[0] += bias; v[1] += bias; v[2] += bias; v[3] += bias;
        *(f32x4*)&C[((size_t)s * 2048 + n) * 64 + mt * 16 + l4] = v;
      }
    }
  } else {
#pragma unroll
    for (int nt = 0; nt < 4; ++nt) {
      int n = n0 + h_n + nt * 16 + l16;
      float bias = sbias[h_n + nt * 16 + l16];
#pragma unroll
      for (int mt = 0; mt < 4; ++mt) {
#pragma unroll
        for (int r = 0; r < 4; ++r) {
          int m = m0 + h_m + mt * 16 + l4 + r;
          C[((size_t)(m & 63) * 512 + n) * 128 + (m >> 6)] = acc[mt][nt][r] + bias;
        }
      }
    }
  }
}

// ---------------------------------------------------------------------------
// Persistent encoder layer: K=256, ring ringE[129][2][frag-native 64x256].
// LOUT=0: lout bf16 [8192][512] (feeds layer-1 GEMM). LOUT=1: bf16 [64][128][512].
template<int LOUT>
__global__ __launch_bounds__(256, 1) void enc_persist(
    const float* __restrict__ GT,     // [128][2048][64] input gates fp32
    const float* __restrict__ whh,    // [2][1024][256] this layer fp32
    ushort_t* __restrict__ ringE,     // [129][2][16384] bf16 frag-native
    ushort_t* __restrict__ lout,
    ushort_t* __restrict__ hFin,      // dec ring slot0 (frag-native [64][1024])
    float* __restrict__ cFin,         // [512][64] fp32
    unsigned* bar) {
  int nb = blockIdx.x;
  int d = nb >> 7, nbL = nb & 127;
  int tid = threadIdx.x;
  int lane = tid & 63;
  int wv = __builtin_amdgcn_readfirstlane(tid >> 6);
  int l16 = lane & 15, kg = lane >> 4;
  __shared__ ushort_t wE[16 * 264];

  for (int idx = tid; idx < 16 * 256; idx += 256) {
    int m = idx >> 8, k = idx & 255;
    float v = 0.f;
    if (m < 8)
      v = whh[(size_t)d * 262144 +
              (size_t)((m & 3) * 256 + nbL + 128 * (m >> 2)) * 256 + k];
    wE[m * 264 + k] = f2bf(v);
  }
  __syncthreads();

  int b = wv * 16 + l16;
  int hu = nbL + 128 * kg;            // epilogue lanes (<32)
  float creg = 0.f;
  const ushort_t* wp = wE + l16 * 264 + kg * 8;

  for (int t = 0; t < SS; ++t) {
    int s = d ? (SS - 1 - t) : t;
    const ushort_t* xb = ringE + (size_t)(t * 2 + d) * 16384 +
                         wv * 512 + l16 * 32 + kg * 8;
    bf16x8 bfr[8];
#pragma unroll
    for (int ks = 0; ks < 8; ++ks) bfr[ks] = *(const bf16x8*)(xb + ks * 2048);
    float gi[4];
    if (lane < 32) {
#pragma unroll
      for (int r = 0; r < 4; ++r)
        gi[r] = GT[((size_t)s * 2048 + d * 1024 + r * 256 + hu) * 64 + b];
    }
    f32x4 acc = {0.f, 0.f, 0.f, 0.f};
#pragma unroll
    for (int ks = 0; ks < 8; ++ks) {
      bf16x8 af = *(const bf16x8*)(wp + ks * 32);
      acc = __builtin_amdgcn_mfma_f32_16x16x32_bf16(af, bfr[ks], acc, 0, 0, 0);
    }
    if (lane < 32) {
      float g4[4];
#pragma unroll
      for (int r = 0; r < 4; ++r) g4[r] = acc[r] + gi[r];
      float ig = sigf(g4[0]), fg = sigf(g4[1]), gg = tanhf(g4[2]), og = sigf(g4[3]);
      creg = fg * creg + ig * gg;
      float hn = og * tanhf(creg);
      cstoreh(&ringE[(size_t)((t + 1) * 2 + d) * 16384 + xidx(hu, b)], f2bf(hn));
      if (LOUT == 0)
        lout[((size_t)s * 64 + b) * 512 + d * 256 + hu] = f2bf(hn);
      else
        lout[(size_t)b * 65536 + (size_t)s * 512 + d * 256 + hu] = f2bf(hn);
      if (t == SS - 1) {
        hFin[xidx(512 + d * 256 + hu, b)] = f2bf(hn);
        cFin[(d * 256 + hu) * 64 + b] = creg;
      }
    }
    if (t < SS - 1) gbar<NBLK>(bar, (unsigned)(t + 1));
  }
}

// ---------------------------------------------------------------------------
// Persistent decoder, NBD=128 blocks (R14 structure): each block owns 4 hu =
// {nb+128j}, 16 MFMA rows = 4 hu x 4 gates (row m = j*4 + g) -- no pad rows.
// Rings (frag-native [64][1024]): r0 = [feed | h0], r1 = [- | h1], r2 = [ctx | -].
__global__ __launch_bounds__(256, 1) void dec_persist(
    const float* __restrict__ GdT,    // [128][2048][64] emb gates fp32
    const float* __restrict__ w_ih0, const float* __restrict__ w_hh0,
    const float* __restrict__ w_ih1, const float* __restrict__ w_hh1,
    const float* __restrict__ b_ih1, const float* __restrict__ b_hh1,
    const float* __restrict__ attn_w,
    const ushort_t* __restrict__ enc_out,   // [64][128][512] bf16
    const int* __restrict__ src_tokens,
    const float* __restrict__ c0T, const float* __restrict__ c1T,  // [512][64]
    ushort_t* __restrict__ r0, ushort_t* __restrict__ r1,
    ushort_t* __restrict__ r2,
    ushort_t* __restrict__ houtsB,    // [8192][512] bf16
    unsigned* bar) {
  int nb = blockIdx.x;                // 0..127
  int tid = threadIdx.x;
  int lane = tid & 63;
  int wv = __builtin_amdgcn_readfirstlane(tid >> 6);
  int l16 = lane & 15, kg = lane >> 4;
  __shared__ ushort_t wAl[16 * 1032];
  __shared__ ushort_t wBl[16 * 1032];
  __shared__ ushort_t wDl[16 * 1032];
  __shared__ float h1s[512];
  __shared__ float sc[128];

  // ---- stage bf16 weights (once). Row m = j*4+g -> hu = nb+128j, gate g.
  for (int idx = tid; idx < 16384; idx += 256) {
    int m = idx >> 10, k = idx & 1023;
    int j = m >> 2, g = m & 3;
    int row = g * 512 + nb + 128 * j;
    float va = (k < 512) ? w_ih0[(size_t)row * 1024 + 512 + k]
                         : w_hh0[(size_t)row * 512 + (k - 512)];
    float vb = (k < 512) ? w_ih1[(size_t)row * 512 + k]
                         : w_hh1[(size_t)row * 512 + (k - 512)];
    float vd = (m < 4) ? attn_w[(size_t)(nb * 4 + m) * 1024 + k] : 0.f;
    wAl[m * 1032 + k] = f2bf(va);
    wBl[m * 1032 + k] = f2bf(vb);
    wDl[m * 1032 + k] = f2bf(vd);
  }
  __syncthreads();

  int b = wv * 16 + l16;
  int hu = nb + 128 * kg;             // this lane's hu (all 64 lanes active)
  float c0r = c0T[hu * 64 + b];
  float c1r = c1T[hu * 64 + b];
  float bias1[4];
#pragma unroll
  for (int r = 0; r < 4; ++r)
    bias1[r] = b_ih1[r * 512 + hu] + b_hh1[r * 512 + hu];
  const ushort_t* wpA = wAl + l16 * 1032 + kg * 8;
  const ushort_t* wpB = wBl + l16 * 1032 + kg * 8;
  const ushort_t* wpD = wDl + l16 * 1032 + kg * 8;
  int fragoff = wv * 512 + l16 * 32 + kg * 8;   // frag-native wave base

  for (int t = 0; t < TT; ++t) {
    unsigned gb = (unsigned)(t * 4);
    size_t sC = (size_t)t * 65536, sN = (size_t)(t + 1) * 65536;
    // ---- A: cell0, x = [feed(t) | h0(t)] = r0 slot t (ks 0..31) ----
    {
      const ushort_t* xb = r0 + sC + fragoff;
      bf16x8 bfr[32];
#pragma unroll
      for (int ks = 0; ks < 32; ++ks) bfr[ks] = *(const bf16x8*)(xb + ks * 2048);
      float giA[4];
#pragma unroll
      for (int r = 0; r < 4; ++r)
        giA[r] = GdT[((size_t)t * 2048 + r * 512 + hu) * 64 + b];
      f32x4 acc = {0.f, 0.f, 0.f, 0.f};
#pragma unroll
      for (int ks = 0; ks < 32; ++ks) {
        bf16x8 af = *(const bf16x8*)(wpA + ks * 32);
        acc = __builtin_amdgcn_mfma_f32_16x16x32_bf16(af, bfr[ks], acc, 0, 0, 0);
      }
      float g4[4];
#pragma unroll
      for (int r = 0; r < 4; ++r) g4[r] = acc[r] + giA[r];
      float ig = sigf(g4[0]), fg = sigf(g4[1]), gg = tanhf(g4[2]), og = sigf(g4[3]);
      c0r = fg * c0r + ig * gg;
      float hn = og * tanhf(c0r);
      cstoreh(&r0[sN + xidx(512 + hu, b)], f2bf(hn));   // h0(t+1-slot)
    }
    gbar<NBD>(bar, gb + 1);
    // ---- B: cell1, x = [h0(t) from r0 nxt | h1(t-1) from r1 cur] ----
    {
      bf16x8 bfr[32];
      const ushort_t* xh0 = r0 + sN + fragoff;
      const ushort_t* xh1 = r1 + sC + fragoff;
#pragma unroll
      for (int ks = 0; ks < 16; ++ks) bfr[ks] = *(const bf16x8*)(xh0 + (16 + ks) * 2048);
#pragma unroll
      for (int ks = 16; ks < 32; ++ks) bfr[ks] = *(const bf16x8*)(xh1 + ks * 2048);
      f32x4 acc = {0.f, 0.f, 0.f, 0.f};
#pragma unroll
      for (int ks = 0; ks < 32; ++ks) {
        bf16x8 af = *(const bf16x8*)(wpB + ks * 32);
        acc = __builtin_amdgcn_mfma_f32_16x16x32_bf16(af, bfr[ks], acc, 0, 0, 0);
      }
      float g4[4];
#pragma unroll
      for (int r = 0; r < 4; ++r) g4[r] = acc[r] + bias1[r];
      float ig = sigf(g4[0]), fg = sigf(g4[1]), gg = tanhf(g4[2]), og = sigf(g4[3]);
      c1r = fg * c1r + ig * gg;
      float hn = og * tanhf(c1r);
      cstoreh(&r1[sN + xidx(512 + hu, b)], f2bf(hn));   // h1(t)
    }
    gbar<NBD>(bar, gb + 2);
    // ---- C: attention (blocks 0..63, one per batch; bf16 enc_out) ----
    if (nb < 64) {
      const ushort_t* eb = enc_out + (size_t)nb * 65536;
      for (int i = tid; i < 512; i += 256)
        h1s[i] = bf2f(r1[sN + xidx(512 + i, nb)]);
      __syncthreads();
      {
        int s2 = tid >> 1, half = tid & 1;
        const ushort_t* er = eb + (size_t)s2 * 512 + half * 256;
        const float* hh = h1s + half * 256;
        float a = 0.f;
#pragma unroll 4
        for (int k = 0; k < 256; k += 8) {
          bf16x8 ev = *(const bf16x8*)(er + k);
#pragma unroll
          for (int i = 0; i < 8; ++i)
            a += bf2f((ushort_t)ev[i]) * hh[k + i];
        }
        a += __shfl_xor(a, 1);
        if (!half) sc[s2] = (src_tokens[nb * SS + s2] == 0) ? -1e30f : a;
      }
      __syncthreads();
      if (tid < 64) {
        float m = fmaxf(sc[tid], sc[tid + 64]);
        for (int off = 32; off; off >>= 1) m = fmaxf(m, __shfl_xor(m, off));
        float e0 = __expf(sc[tid] - m), e1 = __expf(sc[tid + 64] - m);
        float ssum = e0 + e1;
        for (int off = 32; off; off >>= 1) ssum += __shfl_xor(ssum, off);
        float inv = 1.f / ssum;
        sc[tid] = e0 * inv; sc[tid + 64] = e1 * inv;
      }
      __syncthreads();
      float a0 = 0.f, a1 = 0.f;
      for (int s2 = 0; s2 < 128; ++s2) {
        float p_ = sc[s2];
        const ushort_t* er = eb + (size_t)s2 * 512;
        a0 += p_ * bf2f(er[tid]);
        a1 += p_ * bf2f(er[tid + 256]);
      }
      cstoreh(&r2[sC + xidx(tid, nb)], f2bf(a0));
      cstoreh(&r2[sC + xidx(tid + 256, nb)], f2bf(a1));
    }
    gbar<NBD>(bar, gb + 3);
    // ---- D: outproj tanh([ctx from r2 cur | h1 from r1 nxt] @ wD^T) ----
    {
      bf16x8 bfr[32];
      const ushort_t* xc = r2 + sC + fragoff;
      const ushort_t* xh1 = r1 + sN + fragoff;
#pragma unroll
      for (int ks = 0; ks < 16; ++ks) bfr[ks] = *(const bf16x8*)(xc + ks * 2048);
#pragma unroll
      for (int ks = 16; ks < 32; ++ks) bfr[ks] = *(const bf16x8*)(xh1 + ks * 2048);
      f32x4 acc = {0.f, 0.f, 0.f, 0.f};
#pragma unroll
      for (int ks = 0; ks < 32; ++ks) {
        bf16x8 af = *(const bf16x8*)(wpD + ks * 32);
        acc = __builtin_amdgcn_mfma_f32_16x16x32_bf16(af, bfr[ks], acc, 0, 0, 0);
      }
      if (lane < 16) {   // rows 0-3 (o = nb*4+r) live in lanes 0-15
#pragma unroll
        for (int r = 0; r < 4; ++r) {
          int o = nb * 4 + r;
          float v = tanhf(acc[r]);
          ushort_t vb = f2bf(v);
          cstoreh(&r0[sN + xidx(o, b)], vb);            // feed(t+1-slot)
          houtsB[((size_t)t * 64 + b) * 512 + o] = vb;
        }
      }
    }
    if (t < TT - 1) gbar<NBD>(bar, gb + 4);
  }
}

// ---------------------------------------------------------------------------
extern "C" void kernel_launch(void* const* d_in, const int* in_sizes, int n_in,
                              void* d_out, int out_size, void* d_ws, size_t ws_size,
                              hipStream_t stream) {
  const int*   src_tokens = (const int*)d_in[0];
  const int*   dst        = (const int*)d_in[2];
  const float* emb_in     = (const float*)d_in[3];
  const float* emb_out    = (const float*)d_in[4];
  const float* enc_w_ih0  = (const float*)d_in[5];
  const float* enc_w_ih1  = (const float*)d_in[6];
  const float* enc_w_hh   = (const float*)d_in[7];
  const float* enc_b_ih   = (const float*)d_in[8];
  const float* enc_b_hh   = (const float*)d_in[9];
  const float* dec_w_ih0  = (const float*)d_in[10];
  const float* dec_w_hh0  = (const float*)d_in[11];
  const float* dec_b_ih0  = (const float*)d_in[12];
  const float* dec_b_hh0  = (const float*)d_in[13];
  const float* dec_w_ih1  = (const float*)d_in[14];
  const float* dec_w_hh1  = (const float*)d_in[15];
  const float* dec_b_ih1  = (const float*)d_in[16];
  const float* dec_b_hh1  = (const float*)d_in[17];
  const float* attn_w     = (const float*)d_in[18];
  const float* pred_w     = (const float*)d_in[19];
  const float* pred_b     = (const float*)d_in[20];
  float* out = (float*)d_out;

  float* ws       = (float*)d_ws;
  ushort_t* houtsB = (ushort_t*)ws;                 // [8192][512] bf16
  float* GT       = ws + 4194304;                   // 16,777,216 f
  ushort_t* encOutB = (ushort_t*)(ws + 20971520);   // [64][128][512] bf16 (2,097,152 f)
  ushort_t* predBF  = (ushort_t*)(ws + 23068672);   // [512][512] bf16 -- NOT aliased
  ushort_t* r0    = (ushort_t*)(ws + 25165824);     // 129*65536 bf16 frag-native
  ushort_t* r1    = (ushort_t*)(ws + 29392896);
  ushort_t* r2    = (ushort_t*)(ws + 33619968);     // 128 slots; wBF alias pre-dec
  ushort_t* wBF   = r2;                             // [3][2048][512] bf16 (reads all pre-dec)
  ushort_t* ringE = (ushort_t*)(ws + 37814272);     // 129*2*16384 bf16
  float* c0T      = ws + 39927808;                  // 32,768
  float* c1T      = ws + 39960576;                  // 32,768
  unsigned* barA  = (unsigned*)(ws + 39993344);     // 3 x 8192 uints
  unsigned* barB  = barA + 8192;
  unsigned* barC  = barB + 8192;                    // dec uses 128*16 = 2048
  ushort_t* U     = (ushort_t*)(ws + 40017920);     // [8192][512] bf16 staging

  hipMemsetAsync(barA, 0, 3 * 8192 * sizeof(unsigned), stream);
  hipMemsetAsync(r0, 0, 65536 * sizeof(ushort_t), stream);     // slot 0
  hipMemsetAsync(r1, 0, 65536 * sizeof(ushort_t), stream);     // slot 0
  hipMemsetAsync(ringE, 0, 32768 * sizeof(ushort_t), stream);  // slot 0

  // ---- One-time weight cast (wBF aliases r2 -- consumed before dec;
  //      pred_w goes to predBF which nothing else touches)
  k_castw<<<dim3(2048, 4), 128, 0, stream>>>(enc_w_ih0, enc_w_ih1, dec_w_ih0,
                                             pred_w, wBF, predBF);

  // ---- Encoder ----
  k_embed_bf<<<dim3(8192), 128, 0, stream>>>(emb_in, src_tokens, U, SS);
  gemm_bf<<<dim3(16, 64), 256, 0, stream>>>(U, wBF, enc_b_ih, enc_b_hh, GT, 1);
  enc_persist<0><<<dim3(NBLK), 256, 0, stream>>>(GT, enc_w_hh, ringE, U,
                                                 r0, c0T, barA);
  gemm_bf<<<dim3(16, 64), 256, 0, stream>>>(U, wBF + 1048576,
                                            enc_b_ih + 2048, enc_b_hh + 2048, GT, 1);
  enc_persist<1><<<dim3(NBLK), 256, 0, stream>>>(GT, enc_w_hh + 524288, ringE,
                                                 encOutB, r1, c1T, barB);

  // ---- Decoder precompute (emb part of cell0 gates) ----
  k_embed_bf<<<dim3(8192), 128, 0, stream>>>(emb_out, dst, U, TT);
  gemm_bf<<<dim3(16, 64), 256, 0, stream>>>(U, wBF + 2097152,
                                            dec_b_ih0, dec_b_hh0, GT, 1);

  // ---- Decoder (persistent, 128 blocks, full 16-row tiles) ----
  dec_persist<<<dim3(NBD), 256, 0, stream>>>(
      GT, dec_w_ih0, dec_w_hh0, dec_w_ih1, dec_w_hh1, dec_b_ih1, dec_b_hh1,
      attn_w, encOutB, src_tokens, c0T, c1T, r0, r1, r2, houtsB, barC);

  // ---- Final projection (bf16 MFMA) straight to [B][OUT][T] ----
  gemm_bf<<<dim3(4, 64), 256, 0, stream>>>(houtsB, predBF,
                                           pred_b, nullptr, out, 2);
}